// Round 3
// baseline (2522.476 us; speedup 1.0000x reference)
//
#include <hip/hip_runtime.h>
#include <cstdint>
#include <cstddef>

// Problem constants (B, C, N, K from the reference)
#define BB_ 8
#define CC_ 128
#define NN_ 4096
#define KK_ 8

// ---- Scratch lives inside the out1 region (B*C*N*K = 33,554,432 floats). ----
// Viewed as 1024 slices ("bc" = b*128+c) of 32768 floats each:
//   bc 0        : xx   (dead after k_knn)
//   bc 1..8     : idx[b] bit-cast ints, idx[b][n][k] at IDX_OFF + b*32768 + n*8 + k
//   bc 9..136   : g[b][c][m] at G_OFF + (b*128+c)*4096 + m
// Write-once schedule: k_xx, k_knn, k_gemm write the scratch zones; k_out0 reads
// idx (writes out0 -> different buffer); k_gatherA writes bc 137..1023 (reads
// only bc 1..136); k_gatherB writes bc 0..136 recomputing g on the fly and
// pre-loading its own idx rows (its writes alias only its own rows' idx).
#define XX_OFF  0
#define IDX_OFF 32768
#define G_OFF   294912

__device__ __forceinline__ float lrelu(float v) { return v >= 0.f ? v : 0.01f * v; }

// Phase-A streaming insert, DESC-tie rule: on equal value the NEW element
// (larger m, since each thread's stream is ascending in m) ranks ABOVE equals.
template <int S>
__device__ __forceinline__ void insert_tieup(float (&v)[S], int (&ix)[S], float d, int m) {
  if (d < v[S - 1]) return;              // d == v[S-1] must insert (new above)
  bool bs[S];
#pragma unroll
  for (int s = 0; s < S; ++s) bs[s] = (v[s] > d);   // strict: equal -> new above
#pragma unroll
  for (int s = S - 1; s >= 1; --s) {
    v[s]  = bs[s] ? v[s]  : (bs[s - 1] ? d : v[s - 1]);
    ix[s] = bs[s] ? ix[s] : (bs[s - 1] ? m : ix[s - 1]);
  }
  if (!bs[0]) { v[0] = d; ix[0] = m; }
}

// Merge comparator emulating np.argsort(d)[..., ::-1][..., :k]:
// value DESC, on bitwise-equal values index DESC (reversed stable ascending).
// This is a STRICT TOTAL ORDER over (v, m) pairs with distinct m, so the top-8
// of a candidate multiset is unique regardless of merge tree shape.
template <int S>
__device__ __forceinline__ void insert_ti_desc(float (&v)[S], int (&ix)[S], float d, int m) {
  bool stay = (v[S - 1] > d) || (v[S - 1] == d && ix[S - 1] > m);
  if (stay) return;
  bool bs[S];
#pragma unroll
  for (int s = 0; s < S; ++s) bs[s] = (v[s] > d) || (v[s] == d && ix[s] > m);
#pragma unroll
  for (int s = S - 1; s >= 1; --s) {
    v[s]  = bs[s] ? v[s]  : (bs[s - 1] ? d : v[s - 1]);
    ix[s] = bs[s] ? ix[s] : (bs[s - 1] ? m : ix[s - 1]);
  }
  if (!bs[0]) { v[0] = d; ix[0] = m; }
}

// ---------------- K1: xx[b,n] = sum_c x^2 (numpy: rounded products, sequential adds).
__global__ void k_xx(const float* __restrict__ x, float* __restrict__ out1f) {
  int t = blockIdx.x * 256 + threadIdx.x;
  int b = t >> 12, n = t & (NN_ - 1);
  const float* p = x + ((size_t)b * CC_) * NN_ + n;
  float acc = 0.f;
  {
#pragma clang fp contract(off)
#pragma unroll
    for (int c = 0; c < CC_; ++c) {
      float v = p[(size_t)c * NN_];
      float v2 = v * v;
      acc = acc + v2;
    }
  }
  out1f[XX_OFF + t] = acc;
}

// 16 FMAs x 4 c-lanes; accumulation order per (i,j) identical to previous
// passing kernel (x,y,z,w ascending c within granule, granules ascending).
__device__ __forceinline__ void fma16(float (&acc)[4][4], const float4 (&a)[4],
                                      const float4 (&b)[4]) {
#pragma unroll
  for (int i = 0; i < 4; ++i)
#pragma unroll
    for (int j = 0; j < 4; ++j) {
      acc[i][j] = fmaf(a[i].x, b[j].x, acc[i][j]);
      acc[i][j] = fmaf(a[i].y, b[j].y, acc[i][j]);
      acc[i][j] = fmaf(a[i].z, b[j].z, acc[i][j]);
      acc[i][j] = fmaf(a[i].w, b[j].w, acc[i][j]);
    }
}

// ---------------- K2: fused pairwise-distance + top-8 per row (np-fp32 emulation).
// v4 (this round): occupancy fix. Round-2 post-mortem showed k_knn is
// latency-bound at 2 blocks/CU (Occ 20%, VALU 53-57%, LDS ~50%, conflicts
// negligible). Changes vs the round-1 (1363us) version -- numerics untouched:
//   (a) B tile split into two c-halves, Bs[64][68] staged per half-phase
//       (A stays full [64][132], staged once). LDS tile 66 KiB -> 50.3 KiB.
//   (b) merge scratch 66 KiB -> 18 KiB via intra-wave butterfly pre-merge
//       (shfl_xor 16/32 + exact insert_ti_desc; strict total order => result
//       identical for any merge tree), then a small [4][64][9] LDS merge.
//   => 3 blocks/CU (154/160 KiB), 12 waves/CU, launch_bounds(256,3) so the
//      allocator has 170 VGPR (round-1 used 96: zero spill risk).
//   (c) staging writes as ds_write_b128 (4x fewer LDS write insts, less
//       write-conflict time).
// Accumulation still visits c = 0..127 ascending with the same fmaf chain ->
// acc bit-identical -> idx bit-identical.
__global__ __launch_bounds__(256, 3) void k_knn(const float* __restrict__ x,
                                                float* __restrict__ out1f) {
  __shared__ __align__(16) union S {
    struct {
      float As[64 * 132];  // 33792 B, full c, staged once
      float Bs[64 * 68];   // 17408 B, one 64-c half per phase
      float xxm[64];       //   256 B
    } a;
    struct { float v[4 * 64 * 9]; int i[4 * 64 * 9]; } mg;  // 18432 B (aliases As)
  } s;

  const float* xxz = out1f + XX_OFF;
  int* idxz = (int*)(out1f + IDX_OFF);

  const int blk = blockIdx.x;
  const int b = blk >> 6;              // 64 row-tiles per batch
  const int n0 = (blk & 63) << 6;      // *64
  const float* xb = x + ((size_t)b * CC_) * NN_;
  const int t = threadIdx.x;
  const int tr = t & 15, tc = t >> 4;  // rows tr+16i, cols tc*4+j
  const int r64 = t & 63, wv = t >> 6; // staging: row (=lane), wave id

  // Stage the 64 A-rows (n0..n0+63, all 128 c) once, b128 writes.
  {
#pragma unroll
    for (int q = 0; q < 8; ++q) {
      int g = wv + 4 * q;              // granule 0..31
      float4 tmp;
      tmp.x = xb[(size_t)(4 * g + 0) * NN_ + n0 + r64];
      tmp.y = xb[(size_t)(4 * g + 1) * NN_ + n0 + r64];
      tmp.z = xb[(size_t)(4 * g + 2) * NN_ + n0 + r64];
      tmp.w = xb[(size_t)(4 * g + 3) * NN_ + n0 + r64];
      *reinterpret_cast<float4*>(&s.a.As[r64 * 132 + 4 * g]) = tmp;
    }
  }

  float xr[4];
#pragma unroll
  for (int i = 0; i < 4; ++i) xr[i] = xxz[(b << 12) + n0 + tr + 16 * i];

  float lv[4][8]; int li[4][8];
#pragma unroll
  for (int i = 0; i < 4; ++i)
#pragma unroll
    for (int q = 0; q < 8; ++q) { lv[i][q] = -INFINITY; li[i][q] = 0x7FFFFFFF; }

  const float4* As4 = reinterpret_cast<const float4*>(s.a.As);  // row = 33 granules
  const float4* Bs4 = reinterpret_cast<const float4*>(s.a.Bs);  // row = 17 granules
  int rowA[4], rowB[4];
#pragma unroll
  for (int i = 0; i < 4; ++i) rowA[i] = (tr + 16 * i) * 33;
#pragma unroll
  for (int j = 0; j < 4; ++j) rowB[j] = (tc * 4 + j) * 17;

  for (int m0 = 0; m0 < NN_; m0 += 64) {
    float acc[4][4] = {};
#pragma unroll
    for (int p = 0; p < 2; ++p) {
      __syncthreads();  // protect Bs (prev phase) and xxm (prev chunk's selection)
      {
        // Stage B c-half p: rows m0..m0+63, c in [64p, 64p+64), b128 writes.
#pragma unroll
        for (int q = 0; q < 4; ++q) {
          int gl = wv + 4 * q;         // local granule 0..15
          int c0 = 64 * p + 4 * gl;
          float4 tmp;
          tmp.x = xb[(size_t)(c0 + 0) * NN_ + m0 + r64];
          tmp.y = xb[(size_t)(c0 + 1) * NN_ + m0 + r64];
          tmp.z = xb[(size_t)(c0 + 2) * NN_ + m0 + r64];
          tmp.w = xb[(size_t)(c0 + 3) * NN_ + m0 + r64];
          *reinterpret_cast<float4*>(&s.a.Bs[r64 * 68 + 4 * gl]) = tmp;
        }
        if (p == 0 && t < 64) s.a.xxm[t] = xxz[(b << 12) + m0 + t];
      }
      __syncthreads();

      // 16 granules of this c-half, ascending c (global g = 16p + gl).
#pragma unroll 2
      for (int gl = 0; gl < 16; ++gl) {
        float4 av[4], bv[4];
#pragma unroll
        for (int i = 0; i < 4; ++i) av[i] = As4[rowA[i] + 16 * p + gl];
#pragma unroll
        for (int j = 0; j < 4; ++j) bv[j] = Bs4[rowB[j] + gl];
        fma16(acc, av, bv);
      }
    }

    // Streaming selection (per-thread m-subset ascending; DESC-tie insert).
#pragma unroll
    for (int j = 0; j < 4; ++j) {
      float xm = s.a.xxm[tc * 4 + j];
      int m = m0 + tc * 4 + j;
#pragma unroll
      for (int i = 0; i < 4; ++i) {
        float d = (2.0f * acc[i][j] - xr[i]) - xm;
        insert_tieup<8>(lv[i], li[i], d, m);
      }
    }
  }

  // ---- Merge. Within each wave, the 4 holders of row tr+16i sit at lanes
  // l, l^16, l^32, l^48: butterfly-merge their sorted lists with the exact
  // comparator (total order => unique top-8, merge-tree-independent).
  __syncthreads();  // all tile reads done; As region is dead, mg may alias it
#pragma unroll
  for (int mk = 16; mk <= 32; mk <<= 1) {
#pragma unroll
    for (int i = 0; i < 4; ++i) {
      float pv[8]; int pi[8];
#pragma unroll
      for (int q = 0; q < 8; ++q) {
        pv[q] = __shfl_xor(lv[i][q], mk, 64);
        pi[q] = __shfl_xor(li[i][q], mk, 64);
      }
#pragma unroll
      for (int q = 0; q < 8; ++q) insert_ti_desc<8>(lv[i], li[i], pv[q], pi[q]);
    }
  }
  // One lane per (wave, tr) writes the wave-level top-8 for its 4 rows.
  if ((t & 63) < 16) {
#pragma unroll
    for (int i = 0; i < 4; ++i) {
      int base = wv * 576 + (tr + 16 * i) * 9;   // [4][64][9] padded
#pragma unroll
      for (int q = 0; q < 8; ++q) {
        s.mg.v[base + q] = lv[i][q];
        s.mg.i[base + q] = li[i][q];
      }
    }
  }
  __syncthreads();
  // Final: 64 threads merge the 4 per-wave lists for their row.
  if (t < 64) {
    float bvv[8]; int bii[8];
#pragma unroll
    for (int q = 0; q < 8; ++q) { bvv[q] = s.mg.v[t * 9 + q]; bii[q] = s.mg.i[t * 9 + q]; }
#pragma unroll
    for (int w = 1; w < 4; ++w) {
      int base = w * 576 + t * 9;
#pragma unroll
      for (int q = 0; q < 8; ++q) insert_ti_desc<8>(bvv, bii, s.mg.v[base + q], s.mg.i[base + q]);
    }
    int* op = idxz + (b << 15) + ((n0 + t) << 3);
#pragma unroll
    for (int q = 0; q < KK_; ++q) op[q] = bii[q];
  }
}

// ---------------- K3: g[b,o,m] = sum_c W2[o,c]*lrelu(x[b,c,m]) -> out1 G zone.
__global__ __launch_bounds__(256) void k_gemm(const float* __restrict__ x,
                                              const float* __restrict__ w2,
                                              float* __restrict__ out1f) {
  __shared__ __align__(16) float Ws[64][68];
  __shared__ __align__(16) float Fs[64][68];
  int bb = blockIdx.x >> 7;
  int r = blockIdx.x & 127;
  int o0 = (r >> 6) << 6;   // 0 or 64
  int m0 = (r & 63) << 6;
  const float* xb = x + ((size_t)bb * CC_) * NN_;
  float* gb = out1f + G_OFF + ((size_t)bb * CC_) * NN_;
  int t = threadIdx.x;
  int tm = t & 15, to = t >> 4;

  float acc[4][4] = {};
  for (int cc = 0; cc < CC_; cc += 64) {
    __syncthreads();
    {
      int cl = t & 63, q0 = t >> 6;   // q0 in 0..3
      for (int oo = q0; oo < 64; oo += 4) Ws[oo][cl] = w2[(o0 + oo) * CC_ + cc + cl];
      for (int c2 = q0; c2 < 64; c2 += 4) Fs[cl][c2] = lrelu(xb[(size_t)(cc + c2) * NN_ + m0 + cl]);
    }
    __syncthreads();
#pragma unroll 8
    for (int cq = 0; cq < 64; cq += 4) {
      float4 aw[4], bf[4];
#pragma unroll
      for (int i = 0; i < 4; ++i) aw[i] = *reinterpret_cast<const float4*>(&Ws[to + 16 * i][cq]);
#pragma unroll
      for (int j = 0; j < 4; ++j) bf[j] = *reinterpret_cast<const float4*>(&Fs[tm + 16 * j][cq]);
#pragma unroll
      for (int i = 0; i < 4; ++i)
#pragma unroll
        for (int j = 0; j < 4; ++j) {
          acc[i][j] = fmaf(aw[i].x, bf[j].x, acc[i][j]);
          acc[i][j] = fmaf(aw[i].y, bf[j].y, acc[i][j]);
          acc[i][j] = fmaf(aw[i].z, bf[j].z, acc[i][j]);
          acc[i][j] = fmaf(aw[i].w, bf[j].w, acc[i][j]);
        }
    }
  }
#pragma unroll
  for (int i = 0; i < 4; ++i)
#pragma unroll
    for (int j = 0; j < 4; ++j)
      gb[((size_t)(o0 + to + 16 * i)) * NN_ + m0 + tm + 16 * j] = acc[i][j];
}

// ---------------- K4: out0[b,c,n] = x + (sum_k lrelu(x[.,idx_k]) + lrelu(self))/9.
// Reads idx from out1 scratch, writes out0 (different buffer -> no hazards).
__global__ void k_out0(const float* __restrict__ x, const float* __restrict__ out1f,
                       float* __restrict__ out) {
  __shared__ int idxL[512];   // 64 n * 8 k
  int b = blockIdx.x >> 6, nt = blockIdx.x & 63;
  int n0 = nt << 6;
  int t = threadIdx.x;
  const int* ib = (const int*)(out1f + IDX_OFF) + (b << 15) + (n0 << 3);
  idxL[t] = ib[t];
  idxL[t + 256] = ib[t + 256];
  __syncthreads();
  int nl = t & 63, c0 = t >> 6;
  for (int c = c0; c < CC_; c += 4) {
    const float* row = x + ((size_t)b * CC_ + c) * NN_;
    float self = row[n0 + nl];
    float s = 0.f;
#pragma unroll
    for (int k = 0; k < KK_; ++k) s += lrelu(row[idxL[(nl << 3) + k]]);
    s += lrelu(self);   // reference feats order: 8 grouped then center
    out[((size_t)b * CC_ + c) * NN_ + n0 + nl] = fmaf(s, 1.0f / 9.0f, self);
  }
}

// ---------------- K5: gather for bc = 137..1023 (b=1 c>=9 and b=2..7 all c).
// Reads only scratch slices bc 1..136; writes bc >= 137 -> disjoint, safe.
__global__ void k_gatherA(float* __restrict__ out1f) {
  int bc = 137 + blockIdx.x;
  int b = bc >> 7;
  const int* idxz = (const int*)(out1f + IDX_OFF) + (b << 15);
  const float* gs = out1f + G_OFF + (size_t)bc * (size_t)NN_;
  float* op = out1f + (size_t)bc * 32768;
  for (int e = threadIdx.x; e < 32768; e += 256) {
    op[e] = gs[idxz[e]];
  }
}

// ---------------- K6: produce bc = 0..136 (b=0 all c; b=1 c<=8), overwriting the
// scratch zones. Recomputes g-columns on the fly (no g reads). Pre-loads its own
// 512 idx entries (rows 32T..32T+31 for b=0,1) into LDS before any global write;
// its writes alias only idx entries of its OWN rows, so no cross-block hazard.
__global__ __launch_bounds__(256) void k_gatherB(const float* __restrict__ x,
                                                 const float* __restrict__ w2,
                                                 float* __restrict__ out1f) {
  __shared__ int idxL[512];          // col = bsel*256 + r*8 + k
  __shared__ float xcols[8][128];
  int T = blockIdx.x;                // rows 32T .. 32T+31
  int t = threadIdx.x;
  const int* idxz = (const int*)(out1f + IDX_OFF);
  idxL[t]       = idxz[0 * 32768 + ((T * 32) << 3) + t];
  idxL[t + 256] = idxz[1 * 32768 + ((T * 32) << 3) + t];
  __syncthreads();                   // all idx preloaded before ANY write

  for (int it = 0; it < 64; ++it) {
    int colbase = it * 8;
    {  // load phase: 32 threads per column, 8 columns
      int cg = t >> 5, lane = t & 31;
      int col = colbase + cg;
      int bsel = col >> 8;
      int m = idxL[col];
      const float* xb = x + ((size_t)bsel * CC_) * NN_;
#pragma unroll
      for (int q = 0; q < 4; ++q) {
        int c = lane + 32 * q;
        xcols[cg][c] = lrelu(xb[(size_t)c * NN_ + m]);
      }
    }
    __syncthreads();
    {  // compute phase: thread (cg, c0) does channels c0+32h of column cg
      int cg = t >> 5, c0 = t & 31;
      int col = colbase + cg;
      int bsel = col >> 8;
      int rk = col & 255;
      int n = T * 32 + (rk >> 3);
      int k = rk & 7;
      int hmax = (bsel == 0) ? 4 : 1;
      for (int h = 0; h < hmax; ++h) {
        int c = c0 + 32 * h;
        const float* wr = w2 + c * CC_;
        float acc = 0.f;
#pragma unroll 8
        for (int cc = 0; cc < CC_; ++cc) acc = fmaf(wr[cc], xcols[cg][cc], acc);
        if (bsel == 0 || c <= 8) {
          out1f[(size_t)(bsel * CC_ + c) * 32768 + (n << 3) + k] = acc;
        }
      }
    }
    __syncthreads();
  }
}

extern "C" void kernel_launch(void* const* d_in, const int* in_sizes, int n_in,
                              void* d_out, int out_size, void* d_ws, size_t ws_size,
                              hipStream_t stream) {
  const float* x  = (const float*)d_in[0];
  // d_in[1] (W) is mathematically irrelevant: mean(softmax, axis=2) == 1/9 exactly.
  const float* w2 = (const float*)d_in[2];

  float* out0  = (float*)d_out;
  float* out1f = out0 + (size_t)BB_ * CC_ * NN_;
  (void)d_ws; (void)ws_size;   // zero-workspace design: ws_size may be anything

  k_xx     <<<(BB_ * NN_) / 256,  256, 0, stream>>>(x, out1f);
  k_knn    <<<BB_ * (NN_ / 64),   256, 0, stream>>>(x, out1f);
  k_gemm   <<<BB_ * 128,          256, 0, stream>>>(x, w2, out1f);
  k_out0   <<<BB_ * 64,           256, 0, stream>>>(x, out1f, out0);
  k_gatherA<<<1024 - 137,         256, 0, stream>>>(out1f);
  k_gatherB<<<128,                256, 0, stream>>>(x, w2, out1f);
}

// Round 4
// 2326.892 us; speedup vs baseline: 1.0841x; 1.0841x over previous
//
#include <hip/hip_runtime.h>
#include <cstdint>
#include <cstddef>

// Problem constants (B, C, N, K from the reference)
#define BB_ 8
#define CC_ 128
#define NN_ 4096
#define KK_ 8

// ---- Scratch lives inside the out1 region (B*C*N*K = 33,554,432 floats). ----
// Viewed as 1024 slices ("bc" = b*128+c) of 32768 floats each:
//   bc 0        : xx   (dead after k_knn)
//   bc 1..8     : idx[b] bit-cast ints, idx[b][n][k] at IDX_OFF + b*32768 + n*8 + k
//   bc 9..136   : g[b][c][m] at G_OFF + (b*128+c)*4096 + m
// Write-once schedule: k_xx, k_knn, k_gemm write the scratch zones; k_out0 reads
// idx (writes out0 -> different buffer); k_gatherA writes bc 137..1023 (reads
// only bc 1..136); k_gatherB writes bc 0..136 recomputing g on the fly and
// pre-loading its own idx rows (its writes alias only its own rows' idx).
#define XX_OFF  0
#define IDX_OFF 32768
#define G_OFF   294912

__device__ __forceinline__ float lrelu(float v) { return v >= 0.f ? v : 0.01f * v; }

// Phase-A streaming insert, DESC-tie rule: on equal value the NEW element
// (larger m, since each thread's stream is ascending in m) ranks ABOVE equals.
template <int S>
__device__ __forceinline__ void insert_tieup(float (&v)[S], int (&ix)[S], float d, int m) {
  if (d < v[S - 1]) return;              // d == v[S-1] must insert (new above)
  bool bs[S];
#pragma unroll
  for (int s = 0; s < S; ++s) bs[s] = (v[s] > d);   // strict: equal -> new above
#pragma unroll
  for (int s = S - 1; s >= 1; --s) {
    v[s]  = bs[s] ? v[s]  : (bs[s - 1] ? d : v[s - 1]);
    ix[s] = bs[s] ? ix[s] : (bs[s - 1] ? m : ix[s - 1]);
  }
  if (!bs[0]) { v[0] = d; ix[0] = m; }
}

// Merge comparator emulating np.argsort(d)[..., ::-1][..., :k]:
// value DESC, on bitwise-equal values index DESC (reversed stable ascending).
// This is a STRICT TOTAL ORDER over (v, m) pairs with distinct m, so the top-8
// of a candidate multiset is unique regardless of merge tree shape.
template <int S>
__device__ __forceinline__ void insert_ti_desc(float (&v)[S], int (&ix)[S], float d, int m) {
  bool stay = (v[S - 1] > d) || (v[S - 1] == d && ix[S - 1] > m);
  if (stay) return;
  bool bs[S];
#pragma unroll
  for (int s = 0; s < S; ++s) bs[s] = (v[s] > d) || (v[s] == d && ix[s] > m);
#pragma unroll
  for (int s = S - 1; s >= 1; --s) {
    v[s]  = bs[s] ? v[s]  : (bs[s - 1] ? d : v[s - 1]);
    ix[s] = bs[s] ? ix[s] : (bs[s - 1] ? m : ix[s - 1]);
  }
  if (!bs[0]) { v[0] = d; ix[0] = m; }
}

// ---------------- K1: xx[b,n] = sum_c x^2 (numpy: rounded products, sequential adds).
__global__ void k_xx(const float* __restrict__ x, float* __restrict__ out1f) {
  int t = blockIdx.x * 256 + threadIdx.x;
  int b = t >> 12, n = t & (NN_ - 1);
  const float* p = x + ((size_t)b * CC_) * NN_ + n;
  float acc = 0.f;
  {
#pragma clang fp contract(off)
#pragma unroll
    for (int c = 0; c < CC_; ++c) {
      float v = p[(size_t)c * NN_];
      float v2 = v * v;
      acc = acc + v2;
    }
  }
  out1f[XX_OFF + t] = acc;
}

// ---------------- K2: fused pairwise-distance + top-8 per row (np-fp32 emulation).
// v5 (this round): TLP fix. Post-mortems r1-r3 established k_knn is LATENCY-
// bound: FMA-issue floor is only ~218us, LDS reads are broadcast (tiny real
// traffic, 0 conflicts), but at 512 blocks the grid caps residency at
// 2 blocks/CU = 2 waves/SIMD, so every per-granule lgkmcnt wait (~100cy) is
// exposed. Fix: 32x64 tile -> 1024 blocks -> 4 blocks/CU -> 4 waves/SIMD,
// LDS shrunk to 34.6 KiB (As[32][132] full-c staged once + Bs[64][68] split
// per c-half [r3-verified] + xxm), so 4 blocks fit (138/160 KiB).
// acc[2][4]/thread; launch_bounds(256,4) => 128 VGPR budget (r0's same-shape
// used 68). Merge: r3-verified intra-wave butterfly (shfl_xor 16/32, exact
// comparator, total order => unique result) + tiny [4][32][9] LDS merge.
// Numerics: same fmaf chain c=0..127 ascending per (n,m), same ascending-m
// per-thread stream, same exact merge -> idx bit-identical to r1/r3.
__global__ __launch_bounds__(256, 4) void k_knn(const float* __restrict__ x,
                                                float* __restrict__ out1f) {
  __shared__ __align__(16) union S {
    struct {
      float As[32 * 132];  // 16896 B, full c, staged once
      float Bs[64 * 68];   // 17408 B, one 64-c half per phase
      float xxm[64];       //   256 B
    } a;
    struct { float v[4 * 32 * 9]; int i[4 * 32 * 9]; } mg;  // 9216 B (aliases As)
  } s;

  const float* xxz = out1f + XX_OFF;
  int* idxz = (int*)(out1f + IDX_OFF);

  const int blk = blockIdx.x;
  const int b = blk >> 7;              // 128 row-tiles per batch
  const int n0 = (blk & 127) << 5;     // *32
  const float* xb = x + ((size_t)b * CC_) * NN_;
  const int t = threadIdx.x;
  const int tr = t & 15, tc = t >> 4;  // rows tr+16i (i<2), cols tc*4+j
  const int r64 = t & 63, wv = t >> 6; // B staging: row (=lane), wave id

  // Stage the 32 A-rows (n0..n0+31, all 128 c) once, b128 writes.
  // 8 threads per row: thread covers granules (t>>5) + 8q, q=0..3.
  {
    int r32 = t & 31, g0 = t >> 5;     // g0 in 0..7
#pragma unroll
    for (int q = 0; q < 4; ++q) {
      int g = g0 + 8 * q;              // granule 0..31
      float4 tmp;
      tmp.x = xb[(size_t)(4 * g + 0) * NN_ + n0 + r32];
      tmp.y = xb[(size_t)(4 * g + 1) * NN_ + n0 + r32];
      tmp.z = xb[(size_t)(4 * g + 2) * NN_ + n0 + r32];
      tmp.w = xb[(size_t)(4 * g + 3) * NN_ + n0 + r32];
      *reinterpret_cast<float4*>(&s.a.As[r32 * 132 + 4 * g]) = tmp;
    }
  }

  float xr[2];
#pragma unroll
  for (int i = 0; i < 2; ++i) xr[i] = xxz[(b << 12) + n0 + tr + 16 * i];

  float lv[2][8]; int li[2][8];
#pragma unroll
  for (int i = 0; i < 2; ++i)
#pragma unroll
    for (int q = 0; q < 8; ++q) { lv[i][q] = -INFINITY; li[i][q] = 0x7FFFFFFF; }

  const float4* As4 = reinterpret_cast<const float4*>(s.a.As);  // row = 33 granules
  const float4* Bs4 = reinterpret_cast<const float4*>(s.a.Bs);  // row = 17 granules
  int rowA[2], rowB[4];
#pragma unroll
  for (int i = 0; i < 2; ++i) rowA[i] = (tr + 16 * i) * 33;
#pragma unroll
  for (int j = 0; j < 4; ++j) rowB[j] = (tc * 4 + j) * 17;

  for (int m0 = 0; m0 < NN_; m0 += 64) {
    float acc[2][4] = {};
#pragma unroll
    for (int p = 0; p < 2; ++p) {
      __syncthreads();  // protect Bs (prev phase readers) / xxm (prev selection)
      {
        // Stage B c-half p: rows m0..m0+63, c in [64p, 64p+64), b128 writes.
#pragma unroll
        for (int q = 0; q < 4; ++q) {
          int gl = wv + 4 * q;         // local granule 0..15
          int c0 = 64 * p + 4 * gl;
          float4 tmp;
          tmp.x = xb[(size_t)(c0 + 0) * NN_ + m0 + r64];
          tmp.y = xb[(size_t)(c0 + 1) * NN_ + m0 + r64];
          tmp.z = xb[(size_t)(c0 + 2) * NN_ + m0 + r64];
          tmp.w = xb[(size_t)(c0 + 3) * NN_ + m0 + r64];
          *reinterpret_cast<float4*>(&s.a.Bs[r64 * 68 + 4 * gl]) = tmp;
        }
        if (p == 0 && t < 64) s.a.xxm[t] = xxz[(b << 12) + m0 + t];
      }
      __syncthreads();

      // 16 granules of this c-half, ascending c (global g = 16p + gl).
#pragma unroll 8
      for (int gl = 0; gl < 16; ++gl) {
        float4 av[2], bv[4];
#pragma unroll
        for (int i = 0; i < 2; ++i) av[i] = As4[rowA[i] + 16 * p + gl];
#pragma unroll
        for (int j = 0; j < 4; ++j) bv[j] = Bs4[rowB[j] + gl];
#pragma unroll
        for (int i = 0; i < 2; ++i)
#pragma unroll
          for (int j = 0; j < 4; ++j) {
            acc[i][j] = fmaf(av[i].x, bv[j].x, acc[i][j]);
            acc[i][j] = fmaf(av[i].y, bv[j].y, acc[i][j]);
            acc[i][j] = fmaf(av[i].z, bv[j].z, acc[i][j]);
            acc[i][j] = fmaf(av[i].w, bv[j].w, acc[i][j]);
          }
      }
    }

    // Streaming selection (per-thread m-subset ascending; DESC-tie insert).
#pragma unroll
    for (int j = 0; j < 4; ++j) {
      float xm = s.a.xxm[tc * 4 + j];
      int m = m0 + tc * 4 + j;
#pragma unroll
      for (int i = 0; i < 2; ++i) {
        float d = (2.0f * acc[i][j] - xr[i]) - xm;
        insert_tieup<8>(lv[i], li[i], d, m);
      }
    }
  }

  // ---- Merge. Within each wave, the 4 holders of row tr+16i sit at lanes
  // l, l^16, l^32, l^48: butterfly-merge their sorted lists with the exact
  // comparator (total order => unique top-8, merge-tree-independent).
  __syncthreads();  // all tile reads done; As region is dead, mg may alias it
#pragma unroll
  for (int mk = 16; mk <= 32; mk <<= 1) {
#pragma unroll
    for (int i = 0; i < 2; ++i) {
      float pv[8]; int pi[8];
#pragma unroll
      for (int q = 0; q < 8; ++q) {
        pv[q] = __shfl_xor(lv[i][q], mk, 64);
        pi[q] = __shfl_xor(li[i][q], mk, 64);
      }
#pragma unroll
      for (int q = 0; q < 8; ++q) insert_ti_desc<8>(lv[i], li[i], pv[q], pi[q]);
    }
  }
  // One lane per (wave, tr) writes the wave-level top-8 for its 2 rows.
  if ((t & 63) < 16) {
#pragma unroll
    for (int i = 0; i < 2; ++i) {
      int base = wv * 288 + (tr + 16 * i) * 9;   // [4][32][9] padded
#pragma unroll
      for (int q = 0; q < 8; ++q) {
        s.mg.v[base + q] = lv[i][q];
        s.mg.i[base + q] = li[i][q];
      }
    }
  }
  __syncthreads();
  // Final: 32 threads merge the 4 per-wave lists for their row.
  if (t < 32) {
    float bvv[8]; int bii[8];
#pragma unroll
    for (int q = 0; q < 8; ++q) { bvv[q] = s.mg.v[t * 9 + q]; bii[q] = s.mg.i[t * 9 + q]; }
#pragma unroll
    for (int w = 1; w < 4; ++w) {
      int base = w * 288 + t * 9;
#pragma unroll
      for (int q = 0; q < 8; ++q) insert_ti_desc<8>(bvv, bii, s.mg.v[base + q], s.mg.i[base + q]);
    }
    int* op = idxz + (b << 15) + ((n0 + t) << 3);
#pragma unroll
    for (int q = 0; q < KK_; ++q) op[q] = bii[q];
  }
}

// ---------------- K3: g[b,o,m] = sum_c W2[o,c]*lrelu(x[b,c,m]) -> out1 G zone.
__global__ __launch_bounds__(256) void k_gemm(const float* __restrict__ x,
                                              const float* __restrict__ w2,
                                              float* __restrict__ out1f) {
  __shared__ __align__(16) float Ws[64][68];
  __shared__ __align__(16) float Fs[64][68];
  int bb = blockIdx.x >> 7;
  int r = blockIdx.x & 127;
  int o0 = (r >> 6) << 6;   // 0 or 64
  int m0 = (r & 63) << 6;
  const float* xb = x + ((size_t)bb * CC_) * NN_;
  float* gb = out1f + G_OFF + ((size_t)bb * CC_) * NN_;
  int t = threadIdx.x;
  int tm = t & 15, to = t >> 4;

  float acc[4][4] = {};
  for (int cc = 0; cc < CC_; cc += 64) {
    __syncthreads();
    {
      int cl = t & 63, q0 = t >> 6;   // q0 in 0..3
      for (int oo = q0; oo < 64; oo += 4) Ws[oo][cl] = w2[(o0 + oo) * CC_ + cc + cl];
      for (int c2 = q0; c2 < 64; c2 += 4) Fs[cl][c2] = lrelu(xb[(size_t)(cc + c2) * NN_ + m0 + cl]);
    }
    __syncthreads();
#pragma unroll 8
    for (int cq = 0; cq < 64; cq += 4) {
      float4 aw[4], bf[4];
#pragma unroll
      for (int i = 0; i < 4; ++i) aw[i] = *reinterpret_cast<const float4*>(&Ws[to + 16 * i][cq]);
#pragma unroll
      for (int j = 0; j < 4; ++j) bf[j] = *reinterpret_cast<const float4*>(&Fs[tm + 16 * j][cq]);
#pragma unroll
      for (int i = 0; i < 4; ++i)
#pragma unroll
        for (int j = 0; j < 4; ++j) {
          acc[i][j] = fmaf(aw[i].x, bf[j].x, acc[i][j]);
          acc[i][j] = fmaf(aw[i].y, bf[j].y, acc[i][j]);
          acc[i][j] = fmaf(aw[i].z, bf[j].z, acc[i][j]);
          acc[i][j] = fmaf(aw[i].w, bf[j].w, acc[i][j]);
        }
    }
  }
#pragma unroll
  for (int i = 0; i < 4; ++i)
#pragma unroll
    for (int j = 0; j < 4; ++j)
      gb[((size_t)(o0 + to + 16 * i)) * NN_ + m0 + tm + 16 * j] = acc[i][j];
}

// ---------------- K4: out0[b,c,n] = x + (sum_k lrelu(x[.,idx_k]) + lrelu(self))/9.
// Reads idx from out1 scratch, writes out0 (different buffer -> no hazards).
__global__ void k_out0(const float* __restrict__ x, const float* __restrict__ out1f,
                       float* __restrict__ out) {
  __shared__ int idxL[512];   // 64 n * 8 k
  int b = blockIdx.x >> 6, nt = blockIdx.x & 63;
  int n0 = nt << 6;
  int t = threadIdx.x;
  const int* ib = (const int*)(out1f + IDX_OFF) + (b << 15) + (n0 << 3);
  idxL[t] = ib[t];
  idxL[t + 256] = ib[t + 256];
  __syncthreads();
  int nl = t & 63, c0 = t >> 6;
  for (int c = c0; c < CC_; c += 4) {
    const float* row = x + ((size_t)b * CC_ + c) * NN_;
    float self = row[n0 + nl];
    float s = 0.f;
#pragma unroll
    for (int k = 0; k < KK_; ++k) s += lrelu(row[idxL[(nl << 3) + k]]);
    s += lrelu(self);   // reference feats order: 8 grouped then center
    out[((size_t)b * CC_ + c) * NN_ + n0 + nl] = fmaf(s, 1.0f / 9.0f, self);
  }
}

// ---------------- K5: gather for bc = 137..1023 (b=1 c>=9 and b=2..7 all c).
// Reads only scratch slices bc 1..136; writes bc >= 137 -> disjoint, safe.
__global__ void k_gatherA(float* __restrict__ out1f) {
  int bc = 137 + blockIdx.x;
  int b = bc >> 7;
  const int* idxz = (const int*)(out1f + IDX_OFF) + (b << 15);
  const float* gs = out1f + G_OFF + (size_t)bc * (size_t)NN_;
  float* op = out1f + (size_t)bc * 32768;
  for (int e = threadIdx.x; e < 32768; e += 256) {
    op[e] = gs[idxz[e]];
  }
}

// ---------------- K6: produce bc = 0..136 (b=0 all c; b=1 c<=8), overwriting the
// scratch zones. Recomputes g-columns on the fly (no g reads). Pre-loads its own
// 512 idx entries (rows 32T..32T+31 for b=0,1) into LDS before any global write;
// its writes alias only idx entries of its OWN rows, so no cross-block hazard.
__global__ __launch_bounds__(256) void k_gatherB(const float* __restrict__ x,
                                                 const float* __restrict__ w2,
                                                 float* __restrict__ out1f) {
  __shared__ int idxL[512];          // col = bsel*256 + r*8 + k
  __shared__ float xcols[8][128];
  int T = blockIdx.x;                // rows 32T .. 32T+31
  int t = threadIdx.x;
  const int* idxz = (const int*)(out1f + IDX_OFF);
  idxL[t]       = idxz[0 * 32768 + ((T * 32) << 3) + t];
  idxL[t + 256] = idxz[1 * 32768 + ((T * 32) << 3) + t];
  __syncthreads();                   // all idx preloaded before ANY write

  for (int it = 0; it < 64; ++it) {
    int colbase = it * 8;
    {  // load phase: 32 threads per column, 8 columns
      int cg = t >> 5, lane = t & 31;
      int col = colbase + cg;
      int bsel = col >> 8;
      int m = idxL[col];
      const float* xb = x + ((size_t)bsel * CC_) * NN_;
#pragma unroll
      for (int q = 0; q < 4; ++q) {
        int c = lane + 32 * q;
        xcols[cg][c] = lrelu(xb[(size_t)c * NN_ + m]);
      }
    }
    __syncthreads();
    {  // compute phase: thread (cg, c0) does channels c0+32h of column cg
      int cg = t >> 5, c0 = t & 31;
      int col = colbase + cg;
      int bsel = col >> 8;
      int rk = col & 255;
      int n = T * 32 + (rk >> 3);
      int k = rk & 7;
      int hmax = (bsel == 0) ? 4 : 1;
      for (int h = 0; h < hmax; ++h) {
        int c = c0 + 32 * h;
        const float* wr = w2 + c * CC_;
        float acc = 0.f;
#pragma unroll 8
        for (int cc = 0; cc < CC_; ++cc) acc = fmaf(wr[cc], xcols[cg][cc], acc);
        if (bsel == 0 || c <= 8) {
          out1f[(size_t)(bsel * CC_ + c) * 32768 + (n << 3) + k] = acc;
        }
      }
    }
    __syncthreads();
  }
}

extern "C" void kernel_launch(void* const* d_in, const int* in_sizes, int n_in,
                              void* d_out, int out_size, void* d_ws, size_t ws_size,
                              hipStream_t stream) {
  const float* x  = (const float*)d_in[0];
  // d_in[1] (W) is mathematically irrelevant: mean(softmax, axis=2) == 1/9 exactly.
  const float* w2 = (const float*)d_in[2];

  float* out0  = (float*)d_out;
  float* out1f = out0 + (size_t)BB_ * CC_ * NN_;
  (void)d_ws; (void)ws_size;   // zero-workspace design: ws_size may be anything

  k_xx     <<<(BB_ * NN_) / 256,  256, 0, stream>>>(x, out1f);
  k_knn    <<<BB_ * (NN_ / 32),   256, 0, stream>>>(x, out1f);
  k_gemm   <<<BB_ * 128,          256, 0, stream>>>(x, w2, out1f);
  k_out0   <<<BB_ * 64,           256, 0, stream>>>(x, out1f, out0);
  k_gatherA<<<1024 - 137,         256, 0, stream>>>(out1f);
  k_gatherB<<<128,                256, 0, stream>>>(x, w2, out1f);
}